// Round 9
// baseline (1398.853 us; speedup 1.0000x reference)
//
#include <hip/hip_runtime.h>
#include <hip/hip_bf16.h>

#define H 256
#define K2 512
#define BM 32
#define THREADS 512
#define TILE_B 16384          // one staged K-window tile: 256 cols x 32 K x 2B
#define NT 96                 // real tiles: 6 matrices x 16 K-windows
#define NTP 99                // padded (3-deep prefetch overruns by 3)

typedef __attribute__((ext_vector_type(8))) short short8;
typedef __attribute__((ext_vector_type(4))) float f32x4;

struct __align__(8) S4 { short x, y, z, w; };

__device__ __forceinline__ short f2bf(float f) {
    union { float f; unsigned u; } v; v.f = f;
    unsigned r = v.u + 0x7fffu + ((v.u >> 16) & 1u);
    return (short)(r >> 16);
}
__device__ __forceinline__ float bf2f(short s) {
    union { unsigned u; float f; } v; v.u = ((unsigned)(unsigned short)s) << 16;
    return v.f;
}
__device__ __forceinline__ float sigm(float x) { return 1.f / (1.f + __expf(-x)); }
__device__ __forceinline__ float tanh_f(float x) {
    float e = __expf(2.f * x);
    return 1.f - 2.f / (e + 1.f);
}
__device__ __forceinline__ int swz(int row, int kbytes) {
    return ((row << 10) + kbytes) ^ ((row & 7) << 4);
}
__device__ __forceinline__ void gll16(const void* g, void* l) {
    __builtin_amdgcn_global_load_lds((const __attribute__((address_space(1))) void*)g,
                                     (__attribute__((address_space(3))) void*)l, 16, 0, 0);
}

// ---------------- weight/bias prep: pack into per-K-window LDS-image tiles ----------------
// Tile T = p*16 + kwin (p: 0=z_l(g2) 1=z_r(g3) 2=z(g4) 3=r_l(g0) 4=r_r(g1) 5=W2)
// Within tile: [khalf 0..3][col 0..255][e 0..7] bf16, element = M_p[col][kwin*32 + khalf*8 + e]
__global__ void prep_kernel(const float* __restrict__ WL, const float* __restrict__ WR,
                            const float* __restrict__ Wlh, const float* __restrict__ Wrh,
                            const float* __restrict__ bL, const float* __restrict__ bR,
                            const float* __restrict__ blh, const float* __restrict__ brh,
                            short* __restrict__ Wp, float* __restrict__ pb,
                            float* __restrict__ hb) {
    int i = blockIdx.x * blockDim.x + threadIdx.x;
    const int NW = NT * 8192;          // 786432 bf16 elements
    if (i < NW) {
        int T = i >> 13;               // tile
        int r = i & 8191;
        int khalf = r >> 11;
        int col = (r >> 3) & 255;
        int e = r & 7;
        int p = T >> 4, kwin = T & 15;
        int k = kwin * 32 + khalf * 8 + e;
        float v;
        if (p < 5) {
            int g = (p < 3) ? (p + 2) : (p - 3);
            v = (k < H) ? WL[(g * H + col) * H + k] : WR[(g * H + col) * H + (k - H)];
        } else {
            v = (k < H) ? Wlh[col * H + k] : Wrh[col * H + (k - H)];
        }
        Wp[i] = f2bf(v);
        return;
    }
    int j = i - NW;
    if (j < 5 * H) { pb[j] = bL[j] + bR[j]; return; }
    int q = j - 5 * H;
    if (q < H) { hb[q] = blh[q] + brh[q]; }
}

// ---------------- per-level kernel ----------------
__global__ __launch_bounds__(THREADS, 4) void level_kernel(
    const float* __restrict__ curIn, const int* __restrict__ tokens,
    const float* __restrict__ emb, float* __restrict__ curOut,
    const short* __restrict__ Wp, const float* __restrict__ pb,
    const float* __restrict__ hb, int N) {
    __shared__ __align__(16) short A1[BM * K2];        // 32 KB
    __shared__ __align__(16) short Bt[3 * 8192];       // 3 x 16 KB staged weight tiles
    const int tid = threadIdx.x;
    const int n0 = blockIdx.x * BM;

    // ---- A staging: A1[n][0:256]=row 2n, A1[n][256:512]=row 2n+1, swizzled bf16
#pragma unroll
    for (int it = 0; it < 8; ++it) {
        int c = tid + it * THREADS;       // float4 chunk in [0, 4096)
        int r = c >> 6;                   // source row 0..63
        int col = (c & 63) << 2;
        int gr = 2 * n0 + r;
        float4 v = make_float4(0.f, 0.f, 0.f, 0.f);
        if (gr < 2 * N) {
            const float* src = tokens ? (emb + (size_t)tokens[gr] * H)
                                      : (curIn + (size_t)gr * H);
            v = *(const float4*)(src + col);
        }
        int row = r >> 1;
        int kel = ((r & 1) << 8) | col;
        S4 s; s.x = f2bf(v.x); s.y = f2bf(v.y); s.z = f2bf(v.z); s.w = f2bf(v.w);
        *(S4*)((char*)A1 + swz(row, kel * 2)) = s;
    }
    __syncthreads();   // drains vmcnt: clean slate for the B pipeline accounting

    const int wave = tid >> 6, lane = tid & 63;
    const int l15 = lane & 15, khalf = lane >> 4;
    const int col0 = wave * 32;
    const int bofs0 = khalf * 4096 + (col0 + l15) * 16;   // byte offset of b-frag in a tile

    // ---- prologue: stage tiles 0,1,2 into slots 0,1,2 (6 loads in flight)
    {
        const char* src = (const char*)Wp + tid * 16;
        char* dst = (char*)Bt + tid * 16;
        gll16(src, dst);                              gll16(src + 8192, dst + 8192);
        gll16(src + TILE_B, dst + TILE_B);            gll16(src + TILE_B + 8192, dst + TILE_B + 8192);
        gll16(src + 2 * TILE_B, dst + 2 * TILE_B);    gll16(src + 2 * TILE_B + 8192, dst + 2 * TILE_B + 8192);
    }

    float outv[2][2][4];
    float zz[2][2][4];
    f32x4 accRL[2][2];

    for (int p = 0; p < 6; ++p) {
        f32x4 acc[2][2];
#pragma unroll
        for (int rt = 0; rt < 2; ++rt)
#pragma unroll
            for (int ct = 0; ct < 2; ++ct)
                acc[rt][ct] = (f32x4){0.f, 0.f, 0.f, 0.f};

#pragma unroll
        for (int kk = 0; kk < 16; ++kk) {
            int t = p * 16 + kk;
            int slot = t % 3;
            // [B] tile t ready: 2 younger tiles (4 loads) may stay in flight
            asm volatile("s_waitcnt vmcnt(4)" ::: "memory");
            __builtin_amdgcn_sched_barrier(0);
            __builtin_amdgcn_s_barrier();
            // [C] compute on tile t
            const char* Bb = (const char*)Bt + slot * TILE_B;
            short8 a0 = *(const short8*)((const char*)A1 + swz(l15,      kk * 64 + khalf * 16));
            short8 a1 = *(const short8*)((const char*)A1 + swz(16 + l15, kk * 64 + khalf * 16));
            short8 b0 = *(const short8*)(Bb + bofs0);
            short8 b1 = *(const short8*)(Bb + bofs0 + 256);
            acc[0][0] = __builtin_amdgcn_mfma_f32_16x16x32_bf16(a0, b0, acc[0][0], 0, 0, 0);
            acc[1][0] = __builtin_amdgcn_mfma_f32_16x16x32_bf16(a1, b0, acc[1][0], 0, 0, 0);
            acc[0][1] = __builtin_amdgcn_mfma_f32_16x16x32_bf16(a0, b1, acc[0][1], 0, 0, 0);
            acc[1][1] = __builtin_amdgcn_mfma_f32_16x16x32_bf16(a1, b1, acc[1][1], 0, 0, 0);
            // all LDS reads of tile t complete before anyone overwrites slot
            asm volatile("s_waitcnt lgkmcnt(0)" ::: "memory");
            __builtin_amdgcn_sched_barrier(0);
            // [D]
            __builtin_amdgcn_s_barrier();
            __builtin_amdgcn_sched_barrier(0);
            // [E] stage tile t+3 into the slot just freed
            {
                const char* src = (const char*)Wp + (size_t)(t + 3) * TILE_B + tid * 16;
                char* dst = (char*)Bt + slot * TILE_B + tid * 16;
                gll16(src, dst);
                gll16(src + 8192, dst + 8192);
            }
        }

        // ---- pass epilogues ----
        if (p == 0) {                       // z_l: outv = sigm(acc+b)*xl
#pragma unroll
            for (int ct = 0; ct < 2; ++ct) {
                int col = col0 + ct * 16 + l15;
                float bias = pb[2 * H + col];
#pragma unroll
                for (int rt = 0; rt < 2; ++rt)
#pragma unroll
                    for (int j = 0; j < 4; ++j) {
                        int row = rt * 16 + khalf * 4 + j;
                        float zl = sigm(acc[rt][ct][j] + bias);
                        float xl = bf2f(*(const short*)((const char*)A1 + swz(row, col * 2)));
                        outv[rt][ct][j] = zl * xl;
                    }
            }
        } else if (p == 1) {                // z_r: outv += sigm(acc+b)*xr
#pragma unroll
            for (int ct = 0; ct < 2; ++ct) {
                int col = col0 + ct * 16 + l15;
                float bias = pb[3 * H + col];
#pragma unroll
                for (int rt = 0; rt < 2; ++rt)
#pragma unroll
                    for (int j = 0; j < 4; ++j) {
                        int row = rt * 16 + khalf * 4 + j;
                        float zr = sigm(acc[rt][ct][j] + bias);
                        float xr = bf2f(*(const short*)((const char*)A1 + swz(row, (col + 256) * 2)));
                        outv[rt][ct][j] += zr * xr;
                    }
            }
        } else if (p == 2) {                // z
#pragma unroll
            for (int ct = 0; ct < 2; ++ct) {
                int col = col0 + ct * 16 + l15;
                float bias = pb[4 * H + col];
#pragma unroll
                for (int rt = 0; rt < 2; ++rt)
#pragma unroll
                    for (int j = 0; j < 4; ++j)
                        zz[rt][ct][j] = sigm(acc[rt][ct][j] + bias);
            }
        } else if (p == 3) {                // r_l: hold pre-activations
#pragma unroll
            for (int rt = 0; rt < 2; ++rt)
#pragma unroll
                for (int ct = 0; ct < 2; ++ct)
                    accRL[rt][ct] = acc[rt][ct];
        } else if (p == 4) {                // r_l & r_r: write rx into A1 IN PLACE
#pragma unroll
            for (int ct = 0; ct < 2; ++ct) {
                int col = col0 + ct * 16 + l15;
                float bl = pb[col];          // gate 0 bias
                float br = pb[H + col];      // gate 1 bias
#pragma unroll
                for (int rt = 0; rt < 2; ++rt)
#pragma unroll
                    for (int j = 0; j < 4; ++j) {
                        int row = rt * 16 + khalf * 4 + j;
                        int aL = swz(row, col * 2);
                        int aR = swz(row, (col + 256) * 2);
                        float rl = sigm(accRL[rt][ct][j] + bl);
                        float rr = sigm(acc[rt][ct][j] + br);
                        float xl = bf2f(*(const short*)((const char*)A1 + aL));
                        float xr = bf2f(*(const short*)((const char*)A1 + aR));
                        *(short*)((char*)A1 + aL) = f2bf(rl * xl);
                        *(short*)((char*)A1 + aR) = f2bf(rr * xr);
                    }
            }
            asm volatile("s_waitcnt lgkmcnt(0)" ::: "memory");
            __builtin_amdgcn_sched_barrier(0);
            __builtin_amdgcn_s_barrier();   // rx visible to all waves before W2 pass
        } else {                            // p == 5: h_tilde + combine + store
#pragma unroll
            for (int ct = 0; ct < 2; ++ct) {
                int col = col0 + ct * 16 + l15;
                float bias = hb[col];
#pragma unroll
                for (int rt = 0; rt < 2; ++rt)
#pragma unroll
                    for (int j = 0; j < 4; ++j) {
                        int row = rt * 16 + khalf * 4 + j;
                        int gr = n0 + row;
                        float htv = tanh_f(acc[rt][ct][j] + bias);
                        if (gr < N)
                            curOut[(size_t)gr * H + col] =
                                outv[rt][ct][j] + zz[rt][ct][j] * htv;
                    }
            }
        }
    }
    asm volatile("s_waitcnt vmcnt(0) lgkmcnt(0)" ::: "memory");  // drain pad stages
}

// ---------------- finalize: out = (h,h,h) ----------------
__global__ void finalize_kernel(const float* __restrict__ h, float* __restrict__ out) {
    int i = threadIdx.x;
    if (i < 768) out[i] = h[i & 255];
}

extern "C" void kernel_launch(void* const* d_in, const int* in_sizes, int n_in,
                              void* d_out, int out_size, void* d_ws, size_t ws_size,
                              hipStream_t stream) {
    const int*   tokens = (const int*)d_in[0];
    const float* emb    = (const float*)d_in[1];
    const float* WL     = (const float*)d_in[2];
    const float* WR     = (const float*)d_in[3];
    const float* bL     = (const float*)d_in[4];
    const float* bR     = (const float*)d_in[5];
    const float* Wlh    = (const float*)d_in[6];
    const float* Wrh    = (const float*)d_in[7];
    const float* blh    = (const float*)d_in[8];
    const float* brh    = (const float*)d_in[9];

    char* ws = (char*)d_ws;
    short* Wp = (short*)ws;                             // 99 tiles x 16 KB = 1.62 MB
    float* pb = (float*)(ws + (size_t)NTP * TILE_B);    // 5*256 f32
    float* hb = pb + 5 * H;                             // 256 f32
    float* bufB = (float*)(ws + 2 * 1024 * 1024);       // 32768*256 f32
    float* bufA = bufB + (size_t)32768 * H;             // 16384*256 f32

    {
        int total = NT * 8192 + 5 * H + H;
        int blocks = (total + 255) / 256;
        prep_kernel<<<blocks, 256, 0, stream>>>(WL, WR, Wlh, Wrh, bL, bR, blh, brh,
                                                Wp, pb, hb);
    }

    const float* in = nullptr;
    for (int l = 0; l < 16; ++l) {
        int N = 32768 >> l;
        float* out = (l & 1) ? bufA : bufB;
        int blocks = (N + BM - 1) / BM;
        level_kernel<<<blocks, THREADS, 0, stream>>>(
            in, (l == 0) ? tokens : nullptr, emb, out, Wp, pb, hb, N);
        in = out;
    }

    finalize_kernel<<<1, 768, 0, stream>>>(bufA, (float*)d_out);
}